// Round 5
// baseline (403.213 us; speedup 1.0000x reference)
//
#include <hip/hip_runtime.h>
#include <math.h>

#define NA 3
#define NM 32
#define NC 80
#define STRIDE_PX 8.0f
#define THRESH 0.05f
#define NB 16
#define NH 80
#define NW 80
#define NHW (NH * NW)                 // 6400
#define CH (NA * (5 + NC) + NA * NM)  // 351
#define BOXCH (NA * (5 + NC))         // 255
#define TOTAL (NB * NA * NHW)         // 307200
#define CPB 256                       // candidates per block
#define BPA (NHW / CPB)               // 25 blocks per (b,a) pair
#define NBLK (TOTAL / CPB)            // 1200
#define ROWSZ (7 + NM)                // 39
#define WS_ROW_STRIDE (CPB * ROWSZ)   // 9984 floats per block slab
#define EBLK 256                      // emit block size

typedef float f4 __attribute__((ext_vector_type(4)));

__device__ __forceinline__ int wave_sum64(int v) {
#pragma unroll
  for (int s = 32; s > 0; s >>= 1) v += __shfl_xor(v, s, 64);
  return v;
}

// ---- Kernel A: 1 wave/block, 4 candidates/thread, float4 channel loads ----
// Per-candidate math is bit-identical to round 4 (absmax must stay stable).
__global__ __launch_bounds__(64) void decode_kernel(
    const float* __restrict__ in, const float* __restrict__ anchors,
    float* __restrict__ wsrows, int* __restrict__ counts) {
  const int t = threadIdx.x;            // 0..63
  const int bid = blockIdx.x;
  const int b = bid / (NA * BPA);       // block never crosses (b,a): 6400 % 256 == 0
  const int a = (bid / BPA) % NA;
  const int pbase = (bid % BPA) * CPB + t * 4;

  const float* base = in + ((size_t)b * CH + (size_t)a * (5 + NC)) * NHW + pbase;

  f4 tx = *(const f4*)(base + (size_t)0 * NHW);
  f4 ty = *(const f4*)(base + (size_t)1 * NHW);
  f4 tw = *(const f4*)(base + (size_t)2 * NHW);
  f4 th = *(const f4*)(base + (size_t)3 * NHW);
  f4 tob = *(const f4*)(base + (size_t)4 * NHW);

  // 4 independent online-softmax chains (ILP hides exp/fma latency)
  f4 m = {-INFINITY, -INFINITY, -INFINITY, -INFINITY};
  f4 s = {0.f, 0.f, 0.f, 0.f};
  int idx[4] = {0, 0, 0, 0};
#pragma unroll
  for (int j = 0; j < NC; ++j) {
    f4 x = *(const f4*)(base + (size_t)(5 + j) * NHW);
#pragma unroll
    for (int k = 0; k < 4; ++k) {
      float mn = fmaxf(m[k], x[k]);
      s[k] = s[k] * __expf(m[k] - mn) + __expf(x[k] - mn);
      idx[k] = (x[k] > m[k]) ? j : idx[k];
      m[k] = mn;
    }
  }

  float amax = fmaxf(fmaxf(fmaxf(anchors[0], anchors[1]), fmaxf(anchors[2], anchors[3])),
                     fmaxf(anchors[4], anchors[5]));
  float max_value = floorf(logf(1e35f / amax / STRIDE_PX));
  float aw = anchors[a * 2 + 0];
  float ah = anchors[a * 2 + 1];

  bool keep[4];
  float xs[4], ys[4], ww[4], hh[4], sc[4];
#pragma unroll
  for (int k = 0; k < 4; ++k) {
    float cls_max = 1.0f / s[k];
    float obj = 1.0f / (1.0f + __expf(-tob[k]));
    sc[k] = cls_max * obj;
    int p = pbase + k;
    xs[k] = 1.0f / (1.0f + __expf(-tx[k])) + (float)(p % NW);
    ys[k] = 1.0f / (1.0f + __expf(-ty[k])) + (float)(p / NW);
    ww[k] = __expf(fminf(tw[k], max_value)) * aw;
    hh[k] = __expf(fminf(th[k], max_value)) * ah;
    keep[k] = sc[k] > THRESH;
  }

  // wave-local rank in candidate order (lane-major, slot-minor): idx = 4*lane + k
  unsigned long long lowm = (1ull << t) - 1ull;
  unsigned long long ball[4];
  int below = 0, tot = 0;
#pragma unroll
  for (int k = 0; k < 4; ++k) {
    ball[k] = __ballot(keep[k]);
    below += __popcll(ball[k] & lowm);
    tot += __popcll(ball[k]);
  }
  if (t == 0) counts[bid] = tot;

  int rk[4], r = below;
#pragma unroll
  for (int k = 0; k < 4; ++k) { rk[k] = r; r += keep[k] ? 1 : 0; }

  float* slab = wsrows + (size_t)bid * WS_ROW_STRIDE;
#pragma unroll
  for (int k = 0; k < 4; ++k) {
    if (keep[k]) {
      float* o = slab + (size_t)rk[k] * ROWSZ;
      o[0] = (float)b;
      o[1] = xs[k] * STRIDE_PX;
      o[2] = ys[k] * STRIDE_PX;
      o[3] = ww[k] * STRIDE_PX;
      o[4] = hh[k] * STRIDE_PX;
      o[5 + NM] = sc[k];
      o[6 + NM] = (float)idx[k];
    }
  }

  // mask-coefficient gather: one float4 per channel serves all 4 candidates
  const float* mbase = in + ((size_t)b * CH + BOXCH + (size_t)a * NM) * NHW + pbase;
#pragma unroll
  for (int mm = 0; mm < NM; ++mm) {
    f4 mv = *(const f4*)(mbase + (size_t)mm * NHW);
#pragma unroll
    for (int k = 0; k < 4; ++k)
      if (keep[k]) slab[(size_t)rk[k] * ROWSZ + 5 + mm] = mv[k];
  }
}

// ---- Kernel B: per-block redundant prefix over 1200 counts + dense linear copy ----
__global__ __launch_bounds__(EBLK) void emit_kernel(
    const float* __restrict__ wsrows, const int* __restrict__ counts,
    float* __restrict__ out, int out_size) {
  int bid = blockIdx.x;
  int t = threadIdx.x;

  int partial = 0;
  for (int j = t; j < bid; j += EBLK) partial += counts[j];
  partial = wave_sum64(partial);
  __shared__ int sh[EBLK / 64];
  if ((t & 63) == 0) sh[t >> 6] = partial;
  __syncthreads();
  int off = sh[0] + sh[1] + sh[2] + sh[3];

  int cnt = counts[bid];
  int nelem = cnt * ROWSZ;
  const float* src = wsrows + (size_t)bid * WS_ROW_STRIDE;
  int dbase = off * ROWSZ;
  for (int e = t; e < nelem; e += EBLK) {
    int d = dbase + e;
    if (d < out_size) out[d] = src[e];
  }
}

extern "C" void kernel_launch(void* const* d_in, const int* in_sizes, int n_in,
                              void* d_out, int out_size, void* d_ws, size_t ws_size,
                              hipStream_t stream) {
  const float* in = (const float*)d_in[0];
  const float* anchors = (const float*)d_in[1];

  float* wsrows = (float*)d_ws;  // NBLK * WS_ROW_STRIDE floats (~48 MB)
  int* counts = (int*)((float*)d_ws + (size_t)NBLK * WS_ROW_STRIDE);

  decode_kernel<<<NBLK, 64, 0, stream>>>(in, anchors, wsrows, counts);
  emit_kernel<<<NBLK, EBLK, 0, stream>>>(wsrows, counts, (float*)d_out, out_size);
}

// Round 6
// 261.212 us; speedup vs baseline: 1.5436x; 1.5436x over previous
//
#include <hip/hip_runtime.h>
#include <math.h>

#define NA 3
#define NM 32
#define NC 80
#define STRIDE_PX 8.0f
#define THRESH 0.05f
#define NB 16
#define NH 80
#define NW 80
#define NHW (NH * NW)                 // 6400
#define CH (NA * (5 + NC) + NA * NM)  // 351
#define BOXCH (NA * (5 + NC))         // 255
#define TOTAL (NB * NA * NHW)         // 307200
#define CPB 256                       // candidates per block
#define BPA (NHW / CPB)               // 25 blocks per (b,a) pair
#define NBLK (TOTAL / CPB)            // 1200
#define ROWSZ (7 + NM)                // 39
#define WS_ROW_STRIDE (CPB * ROWSZ)   // 9984 floats per block slab
#define EBLK 256                      // emit block size

typedef float f2 __attribute__((ext_vector_type(2)));

__device__ __forceinline__ int wave_sum64(int v) {
#pragma unroll
  for (int s = 32; s > 0; s >>= 1) v += __shfl_xor(v, s, 64);
  return v;
}

// ---- Kernel A: BLK=128, 2 candidates/thread (float2), batched channel loads ----
// Register pressure bounded: 8-channel load batches, outer loop NOT unrolled
// (round 5's full f4 unroll hit 256 VGPR + 100 MB scratch spill).
// Per-candidate op sequence bit-identical to rounds 4/5 (absmax must stay 1.0).
__global__ __launch_bounds__(128) void decode_kernel(
    const float* __restrict__ in, const float* __restrict__ anchors,
    float* __restrict__ wsrows, int* __restrict__ counts) {
  const int t = threadIdx.x;            // 0..127
  const int bid = blockIdx.x;
  const int b = bid / (NA * BPA);       // block never crosses (b,a): 6400 % 256 == 0
  const int a = (bid / BPA) % NA;
  const int pbase = (bid % BPA) * CPB + t * 2;

  const float* base = in + ((size_t)b * CH + (size_t)a * (5 + NC)) * NHW + pbase;

  f2 tx = *(const f2*)(base + (size_t)0 * NHW);
  f2 ty = *(const f2*)(base + (size_t)1 * NHW);
  f2 tw = *(const f2*)(base + (size_t)2 * NHW);
  f2 th = *(const f2*)(base + (size_t)3 * NHW);
  f2 tob = *(const f2*)(base + (size_t)4 * NHW);

  // 2 independent online-softmax chains; 8-channel load batches (prefetch depth 8)
  f2 m = {-INFINITY, -INFINITY};
  f2 s = {0.f, 0.f};
  int idx[2] = {0, 0};
#pragma unroll 1
  for (int jb = 0; jb < NC; jb += 8) {
    f2 xv[8];
#pragma unroll
    for (int u = 0; u < 8; ++u)
      xv[u] = *(const f2*)(base + (size_t)(5 + jb + u) * NHW);
#pragma unroll
    for (int u = 0; u < 8; ++u) {
      int j = jb + u;
#pragma unroll
      for (int k = 0; k < 2; ++k) {
        float x = xv[u][k];
        float mn = fmaxf(m[k], x);
        s[k] = s[k] * __expf(m[k] - mn) + __expf(x - mn);
        idx[k] = (x > m[k]) ? j : idx[k];
        m[k] = mn;
      }
    }
  }

  float amax = fmaxf(fmaxf(fmaxf(anchors[0], anchors[1]), fmaxf(anchors[2], anchors[3])),
                     fmaxf(anchors[4], anchors[5]));
  float max_value = floorf(logf(1e35f / amax / STRIDE_PX));
  float aw = anchors[a * 2 + 0];
  float ah = anchors[a * 2 + 1];

  bool keep[2];
  float xs[2], ys[2], ww[2], hh[2], sc[2];
#pragma unroll
  for (int k = 0; k < 2; ++k) {
    float cls_max = 1.0f / s[k];
    float obj = 1.0f / (1.0f + __expf(-tob[k]));
    sc[k] = cls_max * obj;
    int p = pbase + k;
    xs[k] = 1.0f / (1.0f + __expf(-tx[k])) + (float)(p % NW);
    ys[k] = 1.0f / (1.0f + __expf(-ty[k])) + (float)(p / NW);
    ww[k] = __expf(fminf(tw[k], max_value)) * aw;
    hh[k] = __expf(fminf(th[k], max_value)) * ah;
    keep[k] = sc[k] > THRESH;
  }

  // block-wide rank in candidate order: thread t covers candidates 2t, 2t+1
  const int lane = t & 63;
  const int wv = t >> 6;
  unsigned long long lowm = (1ull << lane) - 1ull;
  unsigned long long b0 = __ballot(keep[0]);
  unsigned long long b1 = __ballot(keep[1]);
  int below = __popcll(b0 & lowm) + __popcll(b1 & lowm);
  int wtot = __popcll(b0) + __popcll(b1);
  __shared__ int wc[2];
  if (lane == 0) wc[wv] = wtot;
  __syncthreads();
  int rk0 = ((wv == 1) ? wc[0] : 0) + below;
  int rk1 = rk0 + (keep[0] ? 1 : 0);
  if (t == 0) counts[bid] = wc[0] + wc[1];
  int rk[2] = {rk0, rk1};

  float* slab = wsrows + (size_t)bid * WS_ROW_STRIDE;
#pragma unroll
  for (int k = 0; k < 2; ++k) {
    if (keep[k]) {
      float* o = slab + (size_t)rk[k] * ROWSZ;
      o[0] = (float)b;
      o[1] = xs[k] * STRIDE_PX;
      o[2] = ys[k] * STRIDE_PX;
      o[3] = ww[k] * STRIDE_PX;
      o[4] = hh[k] * STRIDE_PX;
      o[5 + NM] = sc[k];
      o[6 + NM] = (float)idx[k];
    }
  }

  // mask-coefficient gather: one float2 per channel serves both candidates
  if (keep[0] || keep[1]) {
    const float* mbase = in + ((size_t)b * CH + BOXCH + (size_t)a * NM) * NHW + pbase;
#pragma unroll 1
    for (int mm = 0; mm < NM; ++mm) {
      f2 mv = *(const f2*)(mbase + (size_t)mm * NHW);
      if (keep[0]) slab[(size_t)rk0 * ROWSZ + 5 + mm] = mv[0];
      if (keep[1]) slab[(size_t)rk1 * ROWSZ + 5 + mm] = mv[1];
    }
  }
}

// ---- Kernel B: per-block redundant prefix over 1200 counts + dense linear copy ----
__global__ __launch_bounds__(EBLK) void emit_kernel(
    const float* __restrict__ wsrows, const int* __restrict__ counts,
    float* __restrict__ out, int out_size) {
  int bid = blockIdx.x;
  int t = threadIdx.x;

  int partial = 0;
  for (int j = t; j < bid; j += EBLK) partial += counts[j];
  partial = wave_sum64(partial);
  __shared__ int sh[EBLK / 64];
  if ((t & 63) == 0) sh[t >> 6] = partial;
  __syncthreads();
  int off = sh[0] + sh[1] + sh[2] + sh[3];

  int cnt = counts[bid];
  int nelem = cnt * ROWSZ;
  const float* src = wsrows + (size_t)bid * WS_ROW_STRIDE;
  int dbase = off * ROWSZ;
  for (int e = t; e < nelem; e += EBLK) {
    int d = dbase + e;
    if (d < out_size) out[d] = src[e];
  }
}

extern "C" void kernel_launch(void* const* d_in, const int* in_sizes, int n_in,
                              void* d_out, int out_size, void* d_ws, size_t ws_size,
                              hipStream_t stream) {
  const float* in = (const float*)d_in[0];
  const float* anchors = (const float*)d_in[1];

  float* wsrows = (float*)d_ws;  // NBLK * WS_ROW_STRIDE floats (~48 MB)
  int* counts = (int*)((float*)d_ws + (size_t)NBLK * WS_ROW_STRIDE);

  decode_kernel<<<NBLK, 128, 0, stream>>>(in, anchors, wsrows, counts);
  emit_kernel<<<NBLK, EBLK, 0, stream>>>(wsrows, counts, (float*)d_out, out_size);
}

// Round 7
// 227.402 us; speedup vs baseline: 1.7731x; 1.1487x over previous
//
#include <hip/hip_runtime.h>
#include <math.h>

#define NA 3
#define NM 32
#define NC 80
#define STRIDE_PX 8.0f
#define THRESH 0.05f
#define NB 16
#define NH 80
#define NW 80
#define NHW (NH * NW)                 // 6400
#define CH (NA * (5 + NC) + NA * NM)  // 351
#define BOXCH (NA * (5 + NC))         // 255
#define TOTAL (NB * NA * NHW)         // 307200
#define BLK 256
#define CPB 256                       // candidates per block
#define BPA (NHW / CPB)               // 25 blocks per (b,a) pair
#define NBLK (TOTAL / CPB)            // 1200
#define ROWSZ (7 + NM)                // 39
#define WS_ROW_STRIDE (CPB * ROWSZ)   // 9984 floats per block slab
#define EBLK 256

typedef float f4 __attribute__((ext_vector_type(4)));

__device__ __forceinline__ int wave_sum64(int v) {
#pragma unroll
  for (int s = 32; s > 0; s >>= 1) v += __shfl_xor(v, s, 64);
  return v;
}

// ---- Kernel A: 1 cand/thread, batch-8 prefetched loads, LDS row staging ----
// Round 6 lesson: scattered sub-line slab stores caused 90 MB write-amp and
// swamped the memory pipe. Rows now staged in LDS (stride 39 => conflict-free
// scatter), then copied densely (float4, full lines) to the slab.
// Per-candidate op sequence bit-identical to rounds 4/5/6 (absmax stays 1.0).
__global__ __launch_bounds__(BLK) void decode_kernel(
    const float* __restrict__ in, const float* __restrict__ anchors,
    float* __restrict__ wsrows, int* __restrict__ counts) {
  __shared__ float rows[CPB * ROWSZ];  // 39936 B
  __shared__ int wc[BLK / 64];

  const int t = threadIdx.x;
  const int bid = blockIdx.x;
  const int b = bid / (NA * BPA);      // block never crosses (b,a): 6400 % 256 == 0
  const int a = (bid / BPA) % NA;
  const int p = (bid % BPA) * CPB + t;

  const float* base = in + ((size_t)b * CH + (size_t)a * (5 + NC)) * NHW + p;

  float tx = base[0];
  float ty = base[(size_t)1 * NHW];
  float tw = base[(size_t)2 * NHW];
  float th = base[(size_t)3 * NHW];
  float tobj = base[(size_t)4 * NHW];

  // online softmax, batch-8 prefetch (bounded registers, deep outstanding loads)
  float m = -INFINITY, s = 0.f;
  int idx = 0;
#pragma unroll 1
  for (int jb = 0; jb < NC; jb += 8) {
    float xv[8];
#pragma unroll
    for (int u = 0; u < 8; ++u)
      xv[u] = base[(size_t)(5 + jb + u) * NHW];
#pragma unroll
    for (int u = 0; u < 8; ++u) {
      float x = xv[u];
      float mn = fmaxf(m, x);
      s = s * __expf(m - mn) + __expf(x - mn);
      idx = (x > m) ? (jb + u) : idx;
      m = mn;
    }
  }

  float cls_max = 1.0f / s;
  float obj = 1.0f / (1.0f + __expf(-tobj));
  float score = cls_max * obj;

  float amax = fmaxf(fmaxf(fmaxf(anchors[0], anchors[1]), fmaxf(anchors[2], anchors[3])),
                     fmaxf(anchors[4], anchors[5]));
  float max_value = floorf(logf(1e35f / amax / STRIDE_PX));
  float aw = anchors[a * 2 + 0];
  float ah = anchors[a * 2 + 1];

  float xs = 1.0f / (1.0f + __expf(-tx)) + (float)(p % NW);
  float ys = 1.0f / (1.0f + __expf(-ty)) + (float)(p / NW);
  float w = __expf(fminf(tw, max_value)) * aw;
  float h = __expf(fminf(th, max_value)) * ah;

  // block-local rank (thread order == candidate order)
  bool keep = score > THRESH;
  unsigned long long ball = __ballot(keep);
  int lane = t & 63;
  int wv = t >> 6;
  int lower = __popcll(ball & ((1ull << lane) - 1ull));
  if (lane == 0) wc[wv] = __popcll(ball);
  __syncthreads();
  int pre = 0;
#pragma unroll
  for (int i = 0; i < BLK / 64; ++i)
    if (i < wv) pre += wc[i];
  int cnt = wc[0] + wc[1] + wc[2] + wc[3];
  int rk = pre + lower;

  if (keep) {
    float* o = rows + rk * ROWSZ;
    o[0] = (float)b;
    o[1] = xs * STRIDE_PX;
    o[2] = ys * STRIDE_PX;
    o[3] = w * STRIDE_PX;
    o[4] = h * STRIDE_PX;
    o[5 + NM] = score;
    o[6 + NM] = (float)idx;
  }

  // mask gather: coalesced channel loads, conflict-free LDS scatter (stride 39)
  const float* mbase = in + ((size_t)b * CH + BOXCH + (size_t)a * NM) * NHW + p;
#pragma unroll 1
  for (int mb = 0; mb < NM; mb += 8) {
    float mv[8];
#pragma unroll
    for (int u = 0; u < 8; ++u)
      mv[u] = mbase[(size_t)(mb + u) * NHW];
    if (keep) {
#pragma unroll
      for (int u = 0; u < 8; ++u)
        rows[rk * ROWSZ + 5 + mb + u] = mv[u];
    }
  }

  if (t == 0) counts[bid] = cnt;
  __syncthreads();

  // dense coalesced LDS -> slab copy (full-line stores, no write amplification)
  float* slab = wsrows + (size_t)bid * WS_ROW_STRIDE;
  int nelem = cnt * ROWSZ;
  int n4 = nelem >> 2;
  f4* slab4 = (f4*)slab;
  const f4* rows4 = (const f4*)rows;
  for (int e = t; e < n4; e += BLK) slab4[e] = rows4[e];
  for (int e = (n4 << 2) + t; e < nelem; e += BLK) slab[e] = rows[e];
}

// ---- Kernel B: per-block redundant prefix over 1200 counts + dense linear copy ----
__global__ __launch_bounds__(EBLK) void emit_kernel(
    const float* __restrict__ wsrows, const int* __restrict__ counts,
    float* __restrict__ out, int out_size) {
  int bid = blockIdx.x;
  int t = threadIdx.x;

  int partial = 0;
  for (int j = t; j < bid; j += EBLK) partial += counts[j];
  partial = wave_sum64(partial);
  __shared__ int sh[EBLK / 64];
  if ((t & 63) == 0) sh[t >> 6] = partial;
  __syncthreads();
  int off = sh[0] + sh[1] + sh[2] + sh[3];

  int cnt = counts[bid];
  int nelem = cnt * ROWSZ;
  const float* src = wsrows + (size_t)bid * WS_ROW_STRIDE;
  int dbase = off * ROWSZ;
  for (int e = t; e < nelem; e += EBLK) {
    int d = dbase + e;
    if (d < out_size) out[d] = src[e];
  }
}

extern "C" void kernel_launch(void* const* d_in, const int* in_sizes, int n_in,
                              void* d_out, int out_size, void* d_ws, size_t ws_size,
                              hipStream_t stream) {
  const float* in = (const float*)d_in[0];
  const float* anchors = (const float*)d_in[1];

  float* wsrows = (float*)d_ws;  // NBLK * WS_ROW_STRIDE floats (~48 MB)
  int* counts = (int*)((float*)d_ws + (size_t)NBLK * WS_ROW_STRIDE);

  decode_kernel<<<NBLK, BLK, 0, stream>>>(in, anchors, wsrows, counts);
  emit_kernel<<<NBLK, EBLK, 0, stream>>>(wsrows, counts, (float*)d_out, out_size);
}